// Round 6
// baseline (838.095 us; speedup 1.0000x reference)
//
#include <hip/hip_runtime.h>
#include <math.h>

#define HW 4096
#define FIXUP_THR 4e-3f

typedef _Float16 half8_t __attribute__((ext_vector_type(8)));
typedef _Float16 half4_t __attribute__((ext_vector_type(4)));
typedef float f32x4 __attribute__((ext_vector_type(4)));

// ------- transpose to fp16 planes + per-position sumsq partials -------
// f[b][c][pos] -> plane[pz][pos][c] (fp16); part[cblk][pz*4096+pos] = partial sumsq
__global__ __launch_bounds__(256) void transpose_half(const float* __restrict__ f,
                                                      _Float16* __restrict__ plane,
                                                      float* __restrict__ part,
                                                      int C, int b0) {
    __shared__ float tile[64][65];
    const int t = threadIdx.x;
    const int p0 = blockIdx.x * 64;
    const int c0 = blockIdx.y * 64;
    const int pz = blockIdx.z;
    const int b = b0 + pz;
    const float* src = f + ((size_t)b * C + c0) * HW + p0;
    {
        const int cl = t >> 4;
        const int pl = (t & 15) * 4;
#pragma unroll
        for (int it = 0; it < 4; ++it) {
            float4 v = *(const float4*)(src + (size_t)(cl + it * 16) * HW + pl);
            tile[cl + it * 16][pl + 0] = v.x;
            tile[cl + it * 16][pl + 1] = v.y;
            tile[cl + it * 16][pl + 2] = v.z;
            tile[cl + it * 16][pl + 3] = v.w;
        }
    }
    __syncthreads();
    const int pr = t >> 3;
    const int cb = (t & 7) * 8;
#pragma unroll
    for (int it = 0; it < 2; ++it) {
        const int p = pr + it * 32;
        union { _Float16 h[8]; float4 v4; } H;
        float ssq = 0.f;
#pragma unroll
        for (int u = 0; u < 8; ++u) {
            float v = tile[cb + u][p];
            H.h[u] = (_Float16)v;
            ssq = fmaf(v, v, ssq);
        }
        *(float4*)(plane + ((size_t)pz * HW + p0 + p) * C + c0 + cb) = H.v4;
        ssq += __shfl_down(ssq, 4);
        ssq += __shfl_down(ssq, 2);
        ssq += __shfl_down(ssq, 1);
        if ((t & 7) == 0)
            part[(size_t)blockIdx.y * ((size_t)gridDim.z * 4096) + pz * 4096 + p0 + p] = ssq;
    }
}

// part tensor order t3|s3|t4|s4 ; inv order s3=0, t3=8192, s4=16384, t4=24576 ([b*4096+pos])
__global__ __launch_bounds__(256) void norm_finalize(const float* __restrict__ part,
                                                     float* __restrict__ inv,
                                                     int b0, int nb) {
    const int idx = blockIdx.x * 256 + threadIdx.x;   // 4*nb*4096 total
    const int sh = (nb == 2) ? 13 : 12;
    const int per = nb << 12;
    const int tensor = idx >> sh;
    const int rem = idx & ((1 << sh) - 1);
    const int pz = rem >> 12;
    const int pos = rem & 4095;
    const int nblk[4] = {16, 16, 32, 32};
    const int pofft[4] = {0, 16, 32, 64};
    const int ivoff[4] = {8192, 0, 24576, 16384};
    const float* pt = part + (size_t)pofft[tensor] * per + rem;
    float s = 0.f;
    const int n = nblk[tensor];
    for (int k = 0; k < n; ++k) s += pt[(size_t)k * per];
    inv[ivoff[tensor] + (b0 + pz) * 4096 + pos] = 1.0f / sqrtf(s + 1e-6f);
}

// ---------------- fused dual-level fp16 MFMA correlation GEMM (z = batch) ----------------
// M[b,j,i] = relu(dot3*n3) * relu(dot4*n4)  (fp16), MT[b,i,j] = M[b,j,i]
__global__ __launch_bounds__(256, 3) void corr_fused(
    const _Float16* __restrict__ A3, const _Float16* __restrict__ B3,
    const _Float16* __restrict__ A4, const _Float16* __restrict__ B4,
    const float* __restrict__ inv,
    _Float16* __restrict__ M, _Float16* __restrict__ MT, int b0) {
    __shared__ char lds[32768];   // A tile 128x64 fp16 (16KB) | B tile (16KB)
    const int tid = threadIdx.x;
    const int i0 = blockIdx.x * 128;
    const int j0 = blockIdx.y * 128;
    const int pz = blockIdx.z;
    const int b = b0 + pz;
    const _Float16* A3p = A3 + (size_t)pz * (HW * 1024);
    const _Float16* B3p = B3 + (size_t)pz * (HW * 1024);
    const _Float16* A4p = A4 + (size_t)pz * (HW * 2048);
    const _Float16* B4p = B4 + (size_t)pz * (HW * 2048);
    const float* invA3 = inv + 8192;    // t3
    const float* invB3 = inv + 0;       // s3
    const float* invA4 = inv + 24576;   // t4
    const float* invB4 = inv + 16384;   // s4
    const int lane = tid & 63;
    const int w = tid >> 6;
    const int wj = (w >> 1) * 64, wi = (w & 1) * 64;
    const int quad = lane >> 4;

    // fragment LDS offsets; row stride 128 B (8 chunks of 16 B), chunk swizzle ^(row&7)
    int offA[2][4], offB[2][4];
#pragma unroll
    for (int f = 0; f < 4; ++f) {
        int jr = wj + f * 16 + (lane & 15);
        int baseA = jr * 128 + ((quad ^ (jr & 3)) << 4);
        int xkA = ((jr >> 2) & 1) << 6;
        offA[0][f] = baseA + xkA;
        offA[1][f] = baseA + (64 ^ xkA);
        int ir = wi + f * 16 + (lane & 15);
        int baseB = 16384 + ir * 128 + ((quad ^ (ir & 3)) << 4);
        int xkB = ((ir >> 2) & 1) << 6;
        offB[0][f] = baseB + xkB;
        offB[1][f] = baseB + (64 ^ xkB);
    }

    // staging slot geometry: slot g = s*256+tid; row = (g>>3)&127, chunk = g&7,
    // global chunk = chunk ^ (row&7); issues 0-3 = A tile, 4-7 = B tile
    int srow[8], selem[8];
#pragma unroll
    for (int s = 0; s < 8; ++s) {
        int g = s * 256 + tid;
        srow[s] = (g >> 3) & 127;
        selem[s] = ((g & 7) ^ (srow[s] & 7)) << 3;
    }

    half4_t v3p[4][4];
    f32x4 acc[4][4] = {};

#pragma unroll
    for (int ph = 0; ph < 2; ++ph) {
        const _Float16* Ap = ph ? A4p : A3p;
        const _Float16* Bp = ph ? B4p : B3p;
        const int C = ph ? 2048 : 1024;
        const _Float16* srcs[8];
#pragma unroll
        for (int s = 0; s < 8; ++s) {
            const _Float16* pl = (s < 4) ? Ap : Bp;
            int rbase = (s < 4) ? j0 : i0;
            srcs[s] = pl + (size_t)(rbase + srow[s]) * C + selem[s];
        }
#pragma unroll 1
        for (int kt = 0; kt < C; kt += 64) {
#pragma unroll
            for (int s = 0; s < 8; ++s) {
                __builtin_amdgcn_global_load_lds(
                    (const __attribute__((address_space(1))) void*)(srcs[s]),
                    (__attribute__((address_space(3))) void*)(lds + (s * 256 + tid) * 16),
                    16, 0, 0);
                srcs[s] += 64;
            }
            __syncthreads();
#pragma unroll
            for (int st = 0; st < 2; ++st) {
                half8_t a[4], bb[4];
#pragma unroll
                for (int f = 0; f < 4; ++f) {
                    a[f] = *(const half8_t*)(lds + offA[st][f]);
                    bb[f] = *(const half8_t*)(lds + offB[st][f]);
                }
#pragma unroll
                for (int fy = 0; fy < 4; ++fy)
#pragma unroll
                    for (int fx = 0; fx < 4; ++fx)
                        acc[fy][fx] = __builtin_amdgcn_mfma_f32_16x16x32_f16(
                            a[fy], bb[fx], acc[fy][fx], 0, 0, 0);
            }
            __syncthreads();
        }
        if (ph == 0) {
            // stash relu(corr3) as fp16, reset acc
            const int ib = i0 + wi + (lane & 15);
            float sB[4];
#pragma unroll
            for (int fx = 0; fx < 4; ++fx) sB[fx] = invB3[b * 4096 + ib + fx * 16];
#pragma unroll
            for (int fy = 0; fy < 4; ++fy) {
                const int jb = j0 + wj + fy * 16 + quad * 4;
                float sA[4];
#pragma unroll
                for (int r = 0; r < 4; ++r) sA[r] = invA3[b * 4096 + jb + r];
#pragma unroll
                for (int fx = 0; fx < 4; ++fx)
#pragma unroll
                    for (int r = 0; r < 4; ++r) {
                        v3p[fy][fx][r] =
                            (_Float16)fmaxf(acc[fy][fx][r] * sA[r] * sB[fx], 0.f);
                        acc[fy][fx][r] = 0.f;
                    }
            }
        }
    }

    // final epilogue: level4 relu x stashed level3; C/D: col(i)=lane&15, row(j)=quad*4+r
    const int ib = i0 + wi + (lane & 15);
    float sB[4];
#pragma unroll
    for (int fx = 0; fx < 4; ++fx) sB[fx] = invB4[b * 4096 + ib + fx * 16];
#pragma unroll
    for (int fy = 0; fy < 4; ++fy) {
        const int jb = j0 + wj + fy * 16 + quad * 4;
        float sA[4];
#pragma unroll
        for (int r = 0; r < 4; ++r) sA[r] = invA4[b * 4096 + jb + r];
#pragma unroll
        for (int fx = 0; fx < 4; ++fx) {
            const int ii = ib + fx * 16;
            union { _Float16 h[4]; double d; } pk;
#pragma unroll
            for (int r = 0; r < 4; ++r) {
                float v = fmaxf(acc[fy][fx][r] * sA[r] * sB[fx], 0.f) *
                          (float)v3p[fy][fx][r];
                M[((size_t)b * HW + (jb + r)) * HW + ii] = (_Float16)v;
                pk.h[r] = (_Float16)v;
            }
            *(double*)(MT + ((size_t)b * HW + ii) * HW + jb) = pk.d;
        }
    }
}

// ---------------- wave-per-line soft-argmax, barrier-free ----------------
// grid (1024, b, colmode), 4 waves/block, one 4096-elem line per wave held in 32 VGPRs
__global__ __launch_bounds__(256) void soft_argmax(
    const _Float16* __restrict__ M, const _Float16* __restrict__ MT,
    float* __restrict__ out,
    const float* __restrict__ s3, const float* __restrict__ t3,
    const float* __restrict__ s4, const float* __restrict__ t4,
    const float* __restrict__ inv) {
    const int tid = threadIdx.x;
    const int lane = tid & 63;
    const int line = blockIdx.x * 4 + (tid >> 6);
    const int b = blockIdx.y;
    const int colmode = blockIdx.z;

    // colmode=1 (s2t): lines i (MT rows), candidates j (tgt features)
    const float* cf3 = colmode ? t3 : s3;
    const float* lf3 = colmode ? s3 : t3;
    const float* cf4 = colmode ? t4 : s4;
    const float* lf4 = colmode ? s4 : t4;
    const float* invc3 = inv + (colmode ? 8192 : 0);
    const float* invl3 = inv + (colmode ? 0 : 8192);
    const float* invc4 = inv + (colmode ? 24576 : 16384);
    const float* invl4 = inv + (colmode ? 16384 : 24576);

    const _Float16* src = (colmode ? MT : M) + ((size_t)b * HW + line) * HW;
    half8_t vreg[8];
#pragma unroll
    for (int it = 0; it < 8; ++it)
        vreg[it] = *(const half8_t*)(src + it * 512 + lane * 8);

    // pass 1: sumsq + top-2 (first-index tie-break), all in registers
    float ss = 0.f, v1 = -1.f, v2 = -1.f;
    int i1 = 0, i2 = 0;
#pragma unroll
    for (int it = 0; it < 8; ++it) {
        const int jb = it * 512 + lane * 8;
#pragma unroll
        for (int u = 0; u < 8; ++u) {
            float v = (float)vreg[it][u];
            ss = fmaf(v, v, ss);
            if (v > v1) { v2 = v1; i2 = i1; v1 = v; i1 = jb + u; }
            else if (v > v2) { v2 = v; i2 = jb + u; }
        }
    }
#pragma unroll
    for (int m = 1; m < 64; m <<= 1) {
        ss += __shfl_xor(ss, m);
        float o1 = __shfl_xor(v1, m); int oi1 = __shfl_xor(i1, m);
        float o2 = __shfl_xor(v2, m); int oi2 = __shfl_xor(i2, m);
        if (o1 > v1 || (o1 == v1 && oi1 < i1)) {
            if (v1 > o2 || (v1 == o2 && i1 < oi2)) { v2 = v1; i2 = i1; }
            else { v2 = o2; i2 = oi2; }
            v1 = o1; i1 = oi1;
        } else {
            if (o1 > v2 || (o1 == v2 && oi1 < i2)) { v2 = o1; i2 = oi1; }
        }
    }

    const float inv_l = 1.0f / sqrtf(ss + 1e-6f);
    const float vmax = v1 * inv_l;
    int amax = i1;

    // near-tie fixup: exact fp32 recompute of every candidate within threshold.
    // v1>0 guard: an all-zero line would make every element a candidate.
    const float cut = v1 - FIXUP_THR * v1;
    if (v1 > 0.f && v2 >= cut) {
        float lfr3[16], lfr4[32];
#pragma unroll
        for (int k = 0; k < 16; ++k)
            lfr3[k] = lf3[((size_t)b * 1024 + k * 64 + lane) * HW + line];
#pragma unroll
        for (int k = 0; k < 32; ++k)
            lfr4[k] = lf4[((size_t)b * 2048 + k * 64 + lane) * HW + line];
        float bestE = -1.f;
        int bestI = 1 << 30;
        int budget = 64;
        for (int it = 0; it < 8 && budget > 0; ++it) {
            for (int u = 0; u < 8 && budget > 0; ++u) {
                unsigned long long mask = __ballot((float)vreg[it][u] >= cut);
                while (mask && budget > 0) {
                    int l = __builtin_ctzll(mask);
                    mask &= mask - 1;
                    --budget;
                    int jc = it * 512 + l * 8 + u;
                    float d3 = 0.f, d4 = 0.f;
#pragma unroll
                    for (int k = 0; k < 16; ++k)
                        d3 = fmaf(cf3[((size_t)b * 1024 + k * 64 + lane) * HW + jc],
                                  lfr3[k], d3);
#pragma unroll
                    for (int k = 0; k < 32; ++k)
                        d4 = fmaf(cf4[((size_t)b * 2048 + k * 64 + lane) * HW + jc],
                                  lfr4[k], d4);
#pragma unroll
                    for (int m = 1; m < 64; m <<= 1) {
                        d3 += __shfl_xor(d3, m);
                        d4 += __shfl_xor(d4, m);
                    }
                    float e3 = fmaxf(d3 * invc3[b * 4096 + jc] * invl3[b * 4096 + line], 0.f);
                    float e4 = fmaxf(d4 * invc4[b * 4096 + jc] * invl4[b * 4096 + line], 0.f);
                    float e = e3 * e4;
                    if (e > bestE || (e == bestE && jc < bestI)) { bestE = e; bestI = jc; }
                }
            }
        }
        amax = bestI;
    }

    // pass 2: gaussian-masked softmax expectation (vmax >= masked max: safe shift)
    const float ax = (float)(amax & 63);
    const float ay = (float)(amax >> 6);
    float se = 0.f, sx = 0.f, sy = 0.f;
#pragma unroll
    for (int it = 0; it < 8; ++it) {
        const int jb = it * 512 + lane * 8;
#pragma unroll
        for (int u = 0; u < 8; ++u) {
            int j = jb + u;
            int x2 = j & 63, y2 = j >> 6;
            float dx = (float)x2 - ax, dy = (float)y2 - ay;
            float g = __expf(-(dx * dx + dy * dy) * 0.02f);   // 1/(2*sigma^2)
            float v = g * (float)vreg[it][u] * inv_l;
            float e = __expf(50.0f * (v - vmax));             // beta = 50
            se += e;
            sx = fmaf(e, fmaf((float)x2, 2.0f / 63.0f, -1.0f), sx);
            sy = fmaf(e, fmaf((float)y2, 2.0f / 63.0f, -1.0f), sy);
        }
    }
#pragma unroll
    for (int m = 1; m < 64; m <<= 1) {
        se += __shfl_xor(se, m);
        sx += __shfl_xor(sx, m);
        sy += __shfl_xor(sy, m);
    }
    if (lane == 0) {
        float gx = sx / se;
        float gy = sy / se;
        size_t gbase = colmode ? 0 : 32768;
        size_t fbase = colmode ? 16384 : 49152;
        size_t p = gbase + ((size_t)b * HW + line) * 2;
        out[p] = gx;
        out[p + 1] = gy;
        out[fbase + (size_t)(b * 2 + 0) * HW + line] = 0.f;
        out[fbase + (size_t)(b * 2 + 1) * HW + line] = 0.f;
    }
}

extern "C" void kernel_launch(void* const* d_in, const int* in_sizes, int n_in,
                              void* d_out, int out_size, void* d_ws, size_t ws_size,
                              hipStream_t stream) {
    const float* s3 = (const float*)d_in[0];
    const float* t3 = (const float*)d_in[1];
    const float* s4 = (const float*)d_in[2];
    const float* t4 = (const float*)d_in[3];
    float* out = (float*)d_out;
    char* base = (char*)d_ws;
    float* inv = (float*)base;

    const size_t NEED2 = 238157824ULL;   // combined-batch layout
    if (ws_size >= NEED2) {
        // inv[131072) | part[+3145728) | M16[+67108864) | MT16[+67108864) | P[+100663296)
        float* part = (float*)(base + 131072);
        _Float16* M16 = (_Float16*)(base + 3276800);
        _Float16* MT16 = (_Float16*)(base + 70385664);
        _Float16* P = (_Float16*)(base + 137494528);
        _Float16* P3t = P;
        _Float16* P3s = P + 8388608;
        _Float16* P4t = P + 16777216;
        _Float16* P4s = P + 33554432;

        dim3 g3(64, 16, 2), g4(64, 32, 2);
        transpose_half<<<g3, 256, 0, stream>>>(t3, P3t, part + 0, 1024, 0);
        transpose_half<<<g3, 256, 0, stream>>>(s3, P3s, part + 16 * 8192, 1024, 0);
        transpose_half<<<g4, 256, 0, stream>>>(t4, P4t, part + 32 * 8192, 2048, 0);
        transpose_half<<<g4, 256, 0, stream>>>(s4, P4s, part + 64 * 8192, 2048, 0);
        norm_finalize<<<128, 256, 0, stream>>>(part, inv, 0, 2);
        corr_fused<<<dim3(32, 32, 2), 256, 0, stream>>>(P3t, P3s, P4t, P4s, inv,
                                                        M16, MT16, 0);
        soft_argmax<<<dim3(1024, 2, 2), 256, 0, stream>>>(M16, MT16, out,
                                                          s3, t3, s4, t4, inv);
    } else {
        // per-batch fallback: proven 186.3 MB layout (round 5)
        float* part = (float*)(base + 131072);
        _Float16* M16 = (_Float16*)(base + 1703936);
        _Float16* MT16 = (_Float16*)(base + 68812800);
        _Float16* P = (_Float16*)(base + 135921664);
        _Float16* P3t = P;
        _Float16* P3s = P + 4194304;
        _Float16* P4t = P + 8388608;
        _Float16* P4s = P + 16777216;

        dim3 g3(64, 16, 1), g4(64, 32, 1);
        for (int b0 = 0; b0 < 2; ++b0) {
            transpose_half<<<g3, 256, 0, stream>>>(t3, P3t, part + 0, 1024, b0);
            transpose_half<<<g3, 256, 0, stream>>>(s3, P3s, part + 16 * 4096, 1024, b0);
            transpose_half<<<g4, 256, 0, stream>>>(t4, P4t, part + 32 * 4096, 2048, b0);
            transpose_half<<<g4, 256, 0, stream>>>(s4, P4s, part + 64 * 4096, 2048, b0);
            norm_finalize<<<64, 256, 0, stream>>>(part, inv, b0, 1);
            corr_fused<<<dim3(32, 32, 1), 256, 0, stream>>>(P3t, P3s, P4t, P4s, inv,
                                                            M16, MT16, b0);
        }
        soft_argmax<<<dim3(1024, 2, 2), 256, 0, stream>>>(M16, MT16, out,
                                                          s3, t3, s4, t4, inv);
    }
}